// Round 5
// baseline (7574.952 us; speedup 1.0000x reference)
//
#include <hip/hip_runtime.h>

// DualEncoderLSTMDense: dual peephole-LSTM encoders (shared weights) + M-projection + tiny MLP.
// B=256, L=128, E=256, H=512, VOCAB=90000, NUM_NEG=4, forget_bias=2.0.
//
// Round 5: persistent (NON-cooperative) kernel, 256 blocks x 256 threads = 1 block/CU,
// static LDS exactly 64 KiB (h-part W_hi slice, XOR-swizzled); x-part W_hi and all W_lo
// streamed from L1/L2. c and h live in registers; h published per step as bf16 hi+lo
// planes; per-rowTile (32-block) monotonic device-scope atomic barrier between steps.
// Numerics identical to the passing round 3 (fp32-faithful split matmuls, libm expf/tanhf).

typedef unsigned short u16;
typedef __attribute__((ext_vector_type(8))) short  s16x8;   // 8 bf16 = one MFMA A/B fragment
typedef __attribute__((ext_vector_type(4))) float  f32x4;

#define MFMA(a, b, c) __builtin_amdgcn_mfma_f32_16x16x32_bf16((a), (b), (c), 0, 0, 0)

__device__ __forceinline__ u16 f2bf(float f) {   // RNE float -> bf16
    union { float f; unsigned u; } v; v.f = f;
    unsigned r = v.u + 0x7FFFu + ((v.u >> 16) & 1u);
    return (u16)(r >> 16);
}
__device__ __forceinline__ float bf2f(u16 h) {
    union { unsigned u; float f; } v; v.u = ((unsigned)h) << 16;
    return v.f;
}
__device__ __forceinline__ float sigm(float x) { return 1.0f / (1.0f + expf(-x)); }

// ---- transpose fp32 [R][C] -> bf16 hi/lo planes [C][R] (R,C multiples of 32) ----
__global__ __launch_bounds__(256) void transpose_split(const float* __restrict__ src,
        u16* __restrict__ dhi, u16* __restrict__ dlo, int R, int C)
{
    __shared__ float tile[32][33];
    const int bx = blockIdx.x * 32;   // src col base
    const int by = blockIdx.y * 32;   // src row base
    for (int i = threadIdx.y; i < 32; i += 8)
        tile[i][threadIdx.x] = src[(size_t)(by + i) * C + bx + threadIdx.x];
    __syncthreads();
    for (int i = threadIdx.y; i < 32; i += 8) {
        float v = tile[threadIdx.x][i];
        u16 hi = f2bf(v);
        size_t o = (size_t)(bx + i) * R + by + threadIdx.x;
        dhi[o] = hi;
        dlo[o] = f2bf(v - bf2f(hi));
    }
}

// ---- zero h0 planes + barrier counters ----
__global__ __launch_bounds__(256) void zero_state(u16* __restrict__ h0_hi,
        u16* __restrict__ h0_lo, unsigned* __restrict__ ctr)
{
    const int i = blockIdx.x * 256 + threadIdx.x;   // grid 1024*256 = 262144
    h0_hi[i] = 0;
    h0_lo[i] = 0;
    if (i < 8) ctr[i * 32] = 0;
}

// ---- persistent LSTM: all 128 steps, both encoders (512 batch rows) ----
// 256 blocks (1/CU): rowTile = bid&7 (64 batch rows), hidTile = bid>>3 (16 hid cols).
__global__ __launch_bounds__(256, 1) void lstm_persist(
        const float* __restrict__ emb, const int* __restrict__ qtok, const int* __restrict__ rtok,
        const int* __restrict__ qlen, const int* __restrict__ rlen,
        const u16* __restrict__ Wt_hi, const u16* __restrict__ Wt_lo,   // [2048][768]
        const float* __restrict__ bias, const float* __restrict__ wi,
        const float* __restrict__ wf, const float* __restrict__ wo,
        u16* __restrict__ h0_hi, u16* __restrict__ h0_lo,
        u16* __restrict__ h1_hi, u16* __restrict__ h1_lo,
        unsigned* __restrict__ ctr)
{
    __shared__ u16 whi_h[32768];   // 64 KiB: W_hi rows [4g*16c] x K 256..767, XOR-swizzled

    const int tid = threadIdx.x, lane = tid & 63, w = tid >> 6;
    const int bid = blockIdx.x;
    const int rowTile = bid & 7, hidTile = bid >> 3;
    const int row0 = rowTile * 64 + w * 16, hid0 = hidTile * 16;
    const int frow = lane & 15, kgrp = lane >> 4;
    const int sw = (frow & 7) << 4;                // LDS XOR swizzle for this lane

    // ---- stage h-part W_hi into LDS (once): 64 rows x 64 chunks of 16B ----
    for (int i = tid; i < 4096; i += 256) {
        const int gc = i >> 6, c16 = i & 63;       // W row, 16B chunk within K-slice
        const int g = gc >> 4, cc = gc & 15;
        const s16x8 v = *(const s16x8*)(Wt_hi + (size_t)(g * 512 + hid0 + cc) * 768 + 256 + c16 * 8);
        *(s16x8*)((char*)whi_h + ((gc * 1024 + c16 * 16) ^ ((gc & 7) << 4))) = v;
    }

    // ---- per-thread constants ----
    const int   ohid = hid0 + frow;
    const float bi  = bias[ohid];
    const float bj  = bias[512 + ohid];
    const float bff = bias[1024 + ohid];
    const float bo  = bias[1536 + ohid];
    const float wiv = wi[ohid], wfv = wf[ohid], wov = wo[ohid];
    const int   arow = row0 + frow;                                 // A-fragment row
    const int*  tokp = (arow < 256) ? (qtok + arow * 128) : (rtok + (arow - 256) * 128);
    const u16*  whi_base[4];
    const u16*  wlo_base[4];
    #pragma unroll
    for (int g = 0; g < 4; ++g) {
        whi_base[g] = Wt_hi + (size_t)(g * 512 + hid0 + frow) * 768;
        wlo_base[g] = Wt_lo + (size_t)(g * 512 + hid0 + frow) * 768;
    }
    int lenv[4];
    #pragma unroll
    for (int r = 0; r < 4; ++r) {
        const int rr = row0 + kgrp * 4 + r;
        lenv[r] = (rr < 256) ? qlen[rr] : rlen[rr - 256];
    }
    float c_reg[4] = {0, 0, 0, 0}, h_reg[4] = {0, 0, 0, 0};

    __syncthreads();

    unsigned* myctr = ctr + rowTile * 32;

    for (int t = 0; t < 128; ++t) {
        const u16* rd_hi = (t & 1) ? h1_hi : h0_hi;
        const u16* rd_lo = (t & 1) ? h1_lo : h0_lo;
        u16*       wr_hi = (t & 1) ? h0_hi : h1_hi;
        u16*       wr_lo = (t & 1) ? h0_lo : h1_lo;

        // issue emb gather early (L2/L3 latency hides under h-part MFMAs)
        const int    tok  = tokp[t];
        const float* xrow = emb + (size_t)tok * 256 + kgrp * 8;
        f32x4 fv[16];
        #pragma unroll
        for (int i = 0; i < 16; ++i)
            fv[i] = *(const f32x4*)(xrow + (i >> 1) * 32 + (i & 1) * 4);

        f32x4 acc[4] = {{0,0,0,0},{0,0,0,0},{0,0,0,0},{0,0,0,0}};  // gates i,j,f,o

        const u16* ahp = rd_hi + arow * 512 + kgrp * 8;
        const u16* alp = rd_lo + arow * 512 + kgrp * 8;

        // h-part, K 256..767: bh from LDS, bl streamed; 4 products
        #pragma unroll 2
        for (int ks = 0; ks < 16; ++ks) {
            const int kh = ks * 32;
            const s16x8 ah = *(const s16x8*)(ahp + kh);
            const s16x8 al = *(const s16x8*)(alp + kh);
            #pragma unroll
            for (int g = 0; g < 4; ++g) {
                const int gr = g * 16 + frow;
                const s16x8 bh = *(const s16x8*)((const char*)whi_h + ((gr * 1024 + (kh + kgrp * 8) * 2) ^ sw));
                const s16x8 bl = *(const s16x8*)(wlo_base[g] + 256 + kh + kgrp * 8);
                acc[g] = MFMA(ah, bh, acc[g]);
                acc[g] = MFMA(al, bh, acc[g]);
                acc[g] = MFMA(ah, bl, acc[g]);
                acc[g] = MFMA(al, bl, acc[g]);
            }
        }
        // x-part, K 0..255: split fp32 gather into 2 planes; bh/bl streamed; 3 products
        #pragma unroll
        for (int ks = 0; ks < 8; ++ks) {
            const f32x4 v0 = fv[2 * ks], v1 = fv[2 * ks + 1];
            const float vv[8] = {v0[0], v0[1], v0[2], v0[3], v1[0], v1[1], v1[2], v1[3]};
            s16x8 xh, xl;
            #pragma unroll
            for (int e = 0; e < 8; ++e) {
                const u16 hb = f2bf(vv[e]);
                xh[e] = (short)hb;
                xl[e] = (short)f2bf(vv[e] - bf2f(hb));
            }
            const int kk = ks * 32 + kgrp * 8;
            #pragma unroll
            for (int g = 0; g < 4; ++g) {
                const s16x8 bh = *(const s16x8*)(whi_base[g] + kk);
                const s16x8 bl = *(const s16x8*)(wlo_base[g] + kk);
                acc[g] = MFMA(xh, bh, acc[g]);
                acc[g] = MFMA(xl, bh, acc[g]);
                acc[g] = MFMA(xh, bl, acc[g]);
            }
        }

        // gates + peepholes + masking (state in registers)
        #pragma unroll
        for (int r = 0; r < 4; ++r) {
            const float cold = c_reg[r];
            const float ig = sigm(acc[0][r] + bi + wiv * cold);
            const float jg = tanhf(acc[1][r] + bj);
            const float fg = sigm(acc[2][r] + bff + wfv * cold + 2.0f);
            const float cn = fg * cold + ig * jg;
            const float og = sigm(acc[3][r] + bo + wov * cn);
            const float hn = og * tanhf(cn);
            const bool upd = (t < lenv[r]);
            c_reg[r] = upd ? cn : c_reg[r];
            h_reg[r] = upd ? hn : h_reg[r];
            const int off = (row0 + kgrp * 4 + r) * 512 + ohid;
            const u16 hb = f2bf(h_reg[r]);
            wr_hi[off] = hb;
            wr_lo[off] = f2bf(h_reg[r] - bf2f(hb));
        }

        // per-rowTile barrier (32 blocks), monotonic device-scope counter
        __threadfence();
        __syncthreads();
        if (tid == 0) {
            atomicAdd(myctr, 1u);
            const unsigned target = 32u * (unsigned)(t + 1);
            while (__hip_atomic_load(myctr, __ATOMIC_ACQUIRE, __HIP_MEMORY_SCOPE_AGENT) < target)
                __builtin_amdgcn_s_sleep(1);
        }
        __syncthreads();
        __threadfence();
    }
}

// ---- qt[256][512] = q_h @ M (MFMA, both operands hi+lo, 4 products) ; grid (8,16), 4 waves 2x2 ----
__global__ __launch_bounds__(256) void qt_kernel(
        const u16* __restrict__ h_hi, const u16* __restrict__ h_lo,
        const u16* __restrict__ Mt_hi, const u16* __restrict__ Mt_lo, float* __restrict__ qt)
{
    const int tid = threadIdx.x, lane = tid & 63, w = tid >> 6;
    const int wr = w >> 1, wc = w & 1;
    const int row0 = blockIdx.x * 32 + wr * 16;
    const int col0 = blockIdx.y * 32 + wc * 16;
    const int frow = lane & 15, kgrp = lane >> 4;
    f32x4 acc = {0, 0, 0, 0};
    const u16* aph = h_hi  + (row0 + frow) * 512 + kgrp * 8;
    const u16* apl = h_lo  + (row0 + frow) * 512 + kgrp * 8;
    const u16* bph = Mt_hi + (col0 + frow) * 512 + kgrp * 8;
    const u16* bpl = Mt_lo + (col0 + frow) * 512 + kgrp * 8;
    #pragma unroll 4
    for (int ks = 0; ks < 16; ++ks) {
        s16x8 ah = *(const s16x8*)(aph + ks * 32);
        s16x8 al = *(const s16x8*)(apl + ks * 32);
        s16x8 bh = *(const s16x8*)(bph + ks * 32);
        s16x8 bl = *(const s16x8*)(bpl + ks * 32);
        acc = MFMA(ah, bh, acc);
        acc = MFMA(al, bh, acc);
        acc = MFMA(ah, bl, acc);
        acc = MFMA(al, bl, acc);
    }
    #pragma unroll
    for (int r = 0; r < 4; ++r)
        qt[(row0 + kgrp * 4 + r) * 512 + col0 + frow] = acc[r];
}

// ---- final MLP: 1280 rows, one wave per row ----
__global__ __launch_bounds__(256) void dense_out(const float* __restrict__ qt,
        const u16* __restrict__ h_hi, const u16* __restrict__ h_lo,
        const float* __restrict__ W1, const float* __restrict__ b1,
        const float* __restrict__ W2, const float* __restrict__ b2, float* __restrict__ out)
{
    const int r    = blockIdx.x * 4 + (threadIdx.x >> 6);
    const int lane = threadIdx.x & 63;
    int qi, ri;
    if (r < 256) { qi = r; ri = r; }
    else { const int g = (r - 256) >> 8; const int b = (r - 256) & 255; qi = b; ri = (b + g + 1) & 255; }

    float p[10];
    #pragma unroll
    for (int u = 0; u < 10; ++u) p[u] = 0.0f;
    for (int k = lane; k < 512; k += 64) {
        const float xq = qt[qi * 512 + k];
        #pragma unroll
        for (int u = 0; u < 10; ++u) p[u] += xq * W1[k * 10 + u];
    }
    for (int k = lane; k < 512; k += 64) {
        const int off = (256 + ri) * 512 + k;
        const float xr = bf2f(h_hi[off]) + bf2f(h_lo[off]);
        #pragma unroll
        for (int u = 0; u < 10; ++u) p[u] += xr * W1[(512 + k) * 10 + u];
    }
    #pragma unroll
    for (int off = 32; off; off >>= 1) {
        #pragma unroll
        for (int u = 0; u < 10; ++u) p[u] += __shfl_xor(p[u], off);
    }
    float s = b2[0];
    #pragma unroll
    for (int u = 0; u < 10; ++u) {
        const float h1 = fmaxf(p[u] + b1[u], 0.0f);
        s += h1 * W2[u];
    }
    if (lane == 0) out[r] = fmaxf(s, 0.0f);
}

extern "C" void kernel_launch(void* const* d_in, const int* in_sizes, int n_in,
                              void* d_out, int out_size, void* d_ws, size_t ws_size,
                              hipStream_t stream)
{
    const float* emb  = (const float*)d_in[0];
    const float* Wk   = (const float*)d_in[1];
    const float* bias = (const float*)d_in[2];
    const float* wi   = (const float*)d_in[3];
    const float* wf   = (const float*)d_in[4];
    const float* wo   = (const float*)d_in[5];
    const float* M    = (const float*)d_in[6];
    const float* W1   = (const float*)d_in[7];
    const float* b1   = (const float*)d_in[8];
    const float* W2   = (const float*)d_in[9];
    const float* b2   = (const float*)d_in[10];
    const int*   qtok = (const int*)d_in[11];
    const int*   rtok = (const int*)d_in[12];
    const int*   qlen = (const int*)d_in[13];
    const int*   rlen = (const int*)d_in[14];
    float* out = (float*)d_out;

    // workspace layout (16B-aligned); total ~10 MB
    char* ws = (char*)d_ws;
    u16*      Wt_hi = (u16*)(ws + 0);            // 2048*768*2  = 3,145,728
    u16*      Wt_lo = (u16*)(ws + 3145728);      //               3,145,728
    u16*      Mt_hi = (u16*)(ws + 6291456);      // 512*512*2   =   524,288
    u16*      Mt_lo = (u16*)(ws + 6815744);      //                 524,288
    u16*      h0_hi = (u16*)(ws + 7340032);      //                 524,288
    u16*      h0_lo = (u16*)(ws + 7864320);      //                 524,288
    u16*      h1_hi = (u16*)(ws + 8388608);      //                 524,288
    u16*      h1_lo = (u16*)(ws + 8912896);      //                 524,288
    float*    qt    = (float*)(ws + 9437184);    //                 524,288
    unsigned* ctr   = (unsigned*)(ws + 9961472); // 8 counters @ 128B stride

    transpose_split<<<dim3(64, 24), dim3(32, 8), 0, stream>>>(Wk, Wt_hi, Wt_lo, 768, 2048);
    transpose_split<<<dim3(16, 16), dim3(32, 8), 0, stream>>>(M, Mt_hi, Mt_lo, 512, 512);
    zero_state<<<1024, 256, 0, stream>>>(h0_hi, h0_lo, ctr);

    lstm_persist<<<256, 256, 0, stream>>>(emb, qtok, rtok, qlen, rlen,
                                          Wt_hi, Wt_lo, bias, wi, wf, wo,
                                          h0_hi, h0_lo, h1_hi, h1_lo, ctr);

    // 128 steps (even) => final h lives in the h0 planes
    qt_kernel<<<dim3(8, 16), 256, 0, stream>>>(h0_hi, h0_lo, Mt_hi, Mt_lo, qt);
    dense_out<<<320, 256, 0, stream>>>(qt, h0_hi, h0_lo, W1, b1, W2, b2, out);
}

// Round 6
// 7070.679 us; speedup vs baseline: 1.0713x; 1.0713x over previous
//
#include <hip/hip_runtime.h>

// DualEncoderLSTMDense: dual peephole-LSTM encoders (shared weights) + M-projection + tiny MLP.
// B=256, L=128, E=256, H=512, VOCAB=90000, NUM_NEG=4, forget_bias=2.0.
//
// Round 6: same persistent 256-block structure as round 5, two barrier fixes:
//  (1) spin-poll uses RELAXED atomic loads (round 5's ACQUIRE poll emitted
//      s_waitcnt+buffer_inv EVERY iteration -> L2-invalidate storm, 92% idle);
//      the single __threadfence() after the spin provides acquire.
//  (2) x-part (emb-dependent only) is computed BEFORE the barrier wait, so it
//      overlaps straggler blocks; barrier only guards the h-part.
// Numerics identical to the passing round 3/5 (fp32-faithful split matmuls, libm expf/tanhf).

typedef unsigned short u16;
typedef __attribute__((ext_vector_type(8))) short  s16x8;   // 8 bf16 = one MFMA A/B fragment
typedef __attribute__((ext_vector_type(4))) float  f32x4;

#define MFMA(a, b, c) __builtin_amdgcn_mfma_f32_16x16x32_bf16((a), (b), (c), 0, 0, 0)

__device__ __forceinline__ u16 f2bf(float f) {   // RNE float -> bf16
    union { float f; unsigned u; } v; v.f = f;
    unsigned r = v.u + 0x7FFFu + ((v.u >> 16) & 1u);
    return (u16)(r >> 16);
}
__device__ __forceinline__ float bf2f(u16 h) {
    union { unsigned u; float f; } v; v.u = ((unsigned)h) << 16;
    return v.f;
}
__device__ __forceinline__ float sigm(float x) { return 1.0f / (1.0f + expf(-x)); }

// ---- transpose fp32 [R][C] -> bf16 hi/lo planes [C][R] (R,C multiples of 32) ----
__global__ __launch_bounds__(256) void transpose_split(const float* __restrict__ src,
        u16* __restrict__ dhi, u16* __restrict__ dlo, int R, int C)
{
    __shared__ float tile[32][33];
    const int bx = blockIdx.x * 32;   // src col base
    const int by = blockIdx.y * 32;   // src row base
    for (int i = threadIdx.y; i < 32; i += 8)
        tile[i][threadIdx.x] = src[(size_t)(by + i) * C + bx + threadIdx.x];
    __syncthreads();
    for (int i = threadIdx.y; i < 32; i += 8) {
        float v = tile[threadIdx.x][i];
        u16 hi = f2bf(v);
        size_t o = (size_t)(bx + i) * R + by + threadIdx.x;
        dhi[o] = hi;
        dlo[o] = f2bf(v - bf2f(hi));
    }
}

// ---- zero h0 planes + barrier counters ----
__global__ __launch_bounds__(256) void zero_state(u16* __restrict__ h0_hi,
        u16* __restrict__ h0_lo, unsigned* __restrict__ ctr)
{
    const int i = blockIdx.x * 256 + threadIdx.x;   // grid 1024*256 = 262144
    h0_hi[i] = 0;
    h0_lo[i] = 0;
    if (i < 8) ctr[i * 32] = 0;
}

// ---- persistent LSTM: all 128 steps, both encoders (512 batch rows) ----
// 256 blocks (1/CU): rowTile = bid&7 (64 batch rows), hidTile = bid>>3 (16 hid cols).
__global__ __launch_bounds__(256, 1) void lstm_persist(
        const float* __restrict__ emb, const int* __restrict__ qtok, const int* __restrict__ rtok,
        const int* __restrict__ qlen, const int* __restrict__ rlen,
        const u16* __restrict__ Wt_hi, const u16* __restrict__ Wt_lo,   // [2048][768]
        const float* __restrict__ bias, const float* __restrict__ wi,
        const float* __restrict__ wf, const float* __restrict__ wo,
        u16* __restrict__ h0_hi, u16* __restrict__ h0_lo,
        u16* __restrict__ h1_hi, u16* __restrict__ h1_lo,
        unsigned* __restrict__ ctr)
{
    __shared__ u16 whi_h[32768];   // 64 KiB: W_hi rows [4g*16c] x K 256..767, XOR-swizzled

    const int tid = threadIdx.x, lane = tid & 63, w = tid >> 6;
    const int bid = blockIdx.x;
    const int rowTile = bid & 7, hidTile = bid >> 3;
    const int row0 = rowTile * 64 + w * 16, hid0 = hidTile * 16;
    const int frow = lane & 15, kgrp = lane >> 4;
    const int sw = (frow & 7) << 4;                // LDS XOR swizzle for this lane

    // ---- stage h-part W_hi into LDS (once): 64 rows x 64 chunks of 16B ----
    for (int i = tid; i < 4096; i += 256) {
        const int gc = i >> 6, c16 = i & 63;       // W row, 16B chunk within K-slice
        const int g = gc >> 4, cc = gc & 15;
        const s16x8 v = *(const s16x8*)(Wt_hi + (size_t)(g * 512 + hid0 + cc) * 768 + 256 + c16 * 8);
        *(s16x8*)((char*)whi_h + ((gc * 1024 + c16 * 16) ^ ((gc & 7) << 4))) = v;
    }

    // ---- per-thread constants ----
    const int   ohid = hid0 + frow;
    const float bi  = bias[ohid];
    const float bj  = bias[512 + ohid];
    const float bff = bias[1024 + ohid];
    const float bo  = bias[1536 + ohid];
    const float wiv = wi[ohid], wfv = wf[ohid], wov = wo[ohid];
    const int   arow = row0 + frow;                                 // A-fragment row
    const int*  tokp = (arow < 256) ? (qtok + arow * 128) : (rtok + (arow - 256) * 128);
    const u16*  whi_base[4];
    const u16*  wlo_base[4];
    #pragma unroll
    for (int g = 0; g < 4; ++g) {
        whi_base[g] = Wt_hi + (size_t)(g * 512 + hid0 + frow) * 768;
        wlo_base[g] = Wt_lo + (size_t)(g * 512 + hid0 + frow) * 768;
    }
    int lenv[4];
    #pragma unroll
    for (int r = 0; r < 4; ++r) {
        const int rr = row0 + kgrp * 4 + r;
        lenv[r] = (rr < 256) ? qlen[rr] : rlen[rr - 256];
    }
    float c_reg[4] = {0, 0, 0, 0}, h_reg[4] = {0, 0, 0, 0};

    __syncthreads();

    unsigned* myctr = ctr + rowTile * 32;

    for (int t = 0; t < 128; ++t) {
        const u16* rd_hi = (t & 1) ? h1_hi : h0_hi;
        const u16* rd_lo = (t & 1) ? h1_lo : h0_lo;
        u16*       wr_hi = (t & 1) ? h0_hi : h1_hi;
        u16*       wr_lo = (t & 1) ? h0_lo : h1_lo;

        // ---- x-part FIRST (depends only on tokens; overlaps barrier stragglers) ----
        const int    tok  = tokp[t];
        const float* xrow = emb + (size_t)tok * 256 + kgrp * 8;
        f32x4 fv[16];
        #pragma unroll
        for (int i = 0; i < 16; ++i)
            fv[i] = *(const f32x4*)(xrow + (i >> 1) * 32 + (i & 1) * 4);

        f32x4 acc[4] = {{0,0,0,0},{0,0,0,0},{0,0,0,0},{0,0,0,0}};  // gates i,j,f,o

        // x-part, K 0..255: split fp32 gather into 2 planes; bh/bl streamed; 3 products
        #pragma unroll
        for (int ks = 0; ks < 8; ++ks) {
            const f32x4 v0 = fv[2 * ks], v1 = fv[2 * ks + 1];
            const float vv[8] = {v0[0], v0[1], v0[2], v0[3], v1[0], v1[1], v1[2], v1[3]};
            s16x8 xh, xl;
            #pragma unroll
            for (int e = 0; e < 8; ++e) {
                const u16 hb = f2bf(vv[e]);
                xh[e] = (short)hb;
                xl[e] = (short)f2bf(vv[e] - bf2f(hb));
            }
            const int kk = ks * 32 + kgrp * 8;
            #pragma unroll
            for (int g = 0; g < 4; ++g) {
                const s16x8 bh = *(const s16x8*)(whi_base[g] + kk);
                const s16x8 bl = *(const s16x8*)(wlo_base[g] + kk);
                acc[g] = MFMA(xh, bh, acc[g]);
                acc[g] = MFMA(xl, bh, acc[g]);
                acc[g] = MFMA(xh, bl, acc[g]);
            }
        }

        // ---- barrier wait: all 32 group blocks must have PUBLISHED h(t-1) ----
        // RELAXED poll (no per-iteration cache maintenance); acquire = the one
        // __threadfence() after the spin.
        if (tid == 0) {
            const unsigned target = 32u * (unsigned)t;
            while (__hip_atomic_load(myctr, __ATOMIC_RELAXED, __HIP_MEMORY_SCOPE_AGENT) < target)
                __builtin_amdgcn_s_sleep(2);
        }
        __syncthreads();
        __threadfence();   // acquire: make h(t-1) visible

        const u16* ahp = rd_hi + arow * 512 + kgrp * 8;
        const u16* alp = rd_lo + arow * 512 + kgrp * 8;

        // h-part, K 256..767: bh from LDS, bl streamed; 4 products
        #pragma unroll 2
        for (int ks = 0; ks < 16; ++ks) {
            const int kh = ks * 32;
            const s16x8 ah = *(const s16x8*)(ahp + kh);
            const s16x8 al = *(const s16x8*)(alp + kh);
            #pragma unroll
            for (int g = 0; g < 4; ++g) {
                const int gr = g * 16 + frow;
                const s16x8 bh = *(const s16x8*)((const char*)whi_h + ((gr * 1024 + (kh + kgrp * 8) * 2) ^ sw));
                const s16x8 bl = *(const s16x8*)(wlo_base[g] + 256 + kh + kgrp * 8);
                acc[g] = MFMA(ah, bh, acc[g]);
                acc[g] = MFMA(al, bh, acc[g]);
                acc[g] = MFMA(ah, bl, acc[g]);
                acc[g] = MFMA(al, bl, acc[g]);
            }
        }

        // gates + peepholes + masking (state in registers)
        #pragma unroll
        for (int r = 0; r < 4; ++r) {
            const float cold = c_reg[r];
            const float ig = sigm(acc[0][r] + bi + wiv * cold);
            const float jg = tanhf(acc[1][r] + bj);
            const float fg = sigm(acc[2][r] + bff + wfv * cold + 2.0f);
            const float cn = fg * cold + ig * jg;
            const float og = sigm(acc[3][r] + bo + wov * cn);
            const float hn = og * tanhf(cn);
            const bool upd = (t < lenv[r]);
            c_reg[r] = upd ? cn : c_reg[r];
            h_reg[r] = upd ? hn : h_reg[r];
            const int off = (row0 + kgrp * 4 + r) * 512 + ohid;
            const u16 hb = f2bf(h_reg[r]);
            wr_hi[off] = hb;
            wr_lo[off] = f2bf(h_reg[r] - bf2f(hb));
        }

        // ---- publish: release fence, then one relaxed add per block ----
        __threadfence();   // release: h(t) stores visible before the add
        __syncthreads();
        if (tid == 0)
            __hip_atomic_fetch_add(myctr, 1u, __ATOMIC_RELAXED, __HIP_MEMORY_SCOPE_AGENT);
    }
}

// ---- qt[256][512] = q_h @ M (MFMA, both operands hi+lo, 4 products) ; grid (8,16), 4 waves 2x2 ----
__global__ __launch_bounds__(256) void qt_kernel(
        const u16* __restrict__ h_hi, const u16* __restrict__ h_lo,
        const u16* __restrict__ Mt_hi, const u16* __restrict__ Mt_lo, float* __restrict__ qt)
{
    const int tid = threadIdx.x, lane = tid & 63, w = tid >> 6;
    const int wr = w >> 1, wc = w & 1;
    const int row0 = blockIdx.x * 32 + wr * 16;
    const int col0 = blockIdx.y * 32 + wc * 16;
    const int frow = lane & 15, kgrp = lane >> 4;
    f32x4 acc = {0, 0, 0, 0};
    const u16* aph = h_hi  + (row0 + frow) * 512 + kgrp * 8;
    const u16* apl = h_lo  + (row0 + frow) * 512 + kgrp * 8;
    const u16* bph = Mt_hi + (col0 + frow) * 512 + kgrp * 8;
    const u16* bpl = Mt_lo + (col0 + frow) * 512 + kgrp * 8;
    #pragma unroll 4
    for (int ks = 0; ks < 16; ++ks) {
        s16x8 ah = *(const s16x8*)(aph + ks * 32);
        s16x8 al = *(const s16x8*)(apl + ks * 32);
        s16x8 bh = *(const s16x8*)(bph + ks * 32);
        s16x8 bl = *(const s16x8*)(bpl + ks * 32);
        acc = MFMA(ah, bh, acc);
        acc = MFMA(al, bh, acc);
        acc = MFMA(ah, bl, acc);
        acc = MFMA(al, bl, acc);
    }
    #pragma unroll
    for (int r = 0; r < 4; ++r)
        qt[(row0 + kgrp * 4 + r) * 512 + col0 + frow] = acc[r];
}

// ---- final MLP: 1280 rows, one wave per row ----
__global__ __launch_bounds__(256) void dense_out(const float* __restrict__ qt,
        const u16* __restrict__ h_hi, const u16* __restrict__ h_lo,
        const float* __restrict__ W1, const float* __restrict__ b1,
        const float* __restrict__ W2, const float* __restrict__ b2, float* __restrict__ out)
{
    const int r    = blockIdx.x * 4 + (threadIdx.x >> 6);
    const int lane = threadIdx.x & 63;
    int qi, ri;
    if (r < 256) { qi = r; ri = r; }
    else { const int g = (r - 256) >> 8; const int b = (r - 256) & 255; qi = b; ri = (b + g + 1) & 255; }

    float p[10];
    #pragma unroll
    for (int u = 0; u < 10; ++u) p[u] = 0.0f;
    for (int k = lane; k < 512; k += 64) {
        const float xq = qt[qi * 512 + k];
        #pragma unroll
        for (int u = 0; u < 10; ++u) p[u] += xq * W1[k * 10 + u];
    }
    for (int k = lane; k < 512; k += 64) {
        const int off = (256 + ri) * 512 + k;
        const float xr = bf2f(h_hi[off]) + bf2f(h_lo[off]);
        #pragma unroll
        for (int u = 0; u < 10; ++u) p[u] += xr * W1[(512 + k) * 10 + u];
    }
    #pragma unroll
    for (int off = 32; off; off >>= 1) {
        #pragma unroll
        for (int u = 0; u < 10; ++u) p[u] += __shfl_xor(p[u], off);
    }
    float s = b2[0];
    #pragma unroll
    for (int u = 0; u < 10; ++u) {
        const float h1 = fmaxf(p[u] + b1[u], 0.0f);
        s += h1 * W2[u];
    }
    if (lane == 0) out[r] = fmaxf(s, 0.0f);
}

extern "C" void kernel_launch(void* const* d_in, const int* in_sizes, int n_in,
                              void* d_out, int out_size, void* d_ws, size_t ws_size,
                              hipStream_t stream)
{
    const float* emb  = (const float*)d_in[0];
    const float* Wk   = (const float*)d_in[1];
    const float* bias = (const float*)d_in[2];
    const float* wi   = (const float*)d_in[3];
    const float* wf   = (const float*)d_in[4];
    const float* wo   = (const float*)d_in[5];
    const float* M    = (const float*)d_in[6];
    const float* W1   = (const float*)d_in[7];
    const float* b1   = (const float*)d_in[8];
    const float* W2   = (const float*)d_in[9];
    const float* b2   = (const float*)d_in[10];
    const int*   qtok = (const int*)d_in[11];
    const int*   rtok = (const int*)d_in[12];
    const int*   qlen = (const int*)d_in[13];
    const int*   rlen = (const int*)d_in[14];
    float* out = (float*)d_out;

    // workspace layout (16B-aligned); total ~10 MB
    char* ws = (char*)d_ws;
    u16*      Wt_hi = (u16*)(ws + 0);            // 2048*768*2  = 3,145,728
    u16*      Wt_lo = (u16*)(ws + 3145728);      //               3,145,728
    u16*      Mt_hi = (u16*)(ws + 6291456);      // 512*512*2   =   524,288
    u16*      Mt_lo = (u16*)(ws + 6815744);      //                 524,288
    u16*      h0_hi = (u16*)(ws + 7340032);      //                 524,288
    u16*      h0_lo = (u16*)(ws + 7864320);      //                 524,288
    u16*      h1_hi = (u16*)(ws + 8388608);      //                 524,288
    u16*      h1_lo = (u16*)(ws + 8912896);      //                 524,288
    float*    qt    = (float*)(ws + 9437184);    //                 524,288
    unsigned* ctr   = (unsigned*)(ws + 9961472); // 8 counters @ 128B stride

    transpose_split<<<dim3(64, 24), dim3(32, 8), 0, stream>>>(Wk, Wt_hi, Wt_lo, 768, 2048);
    transpose_split<<<dim3(16, 16), dim3(32, 8), 0, stream>>>(M, Mt_hi, Mt_lo, 512, 512);
    zero_state<<<1024, 256, 0, stream>>>(h0_hi, h0_lo, ctr);

    lstm_persist<<<256, 256, 0, stream>>>(emb, qtok, rtok, qlen, rlen,
                                          Wt_hi, Wt_lo, bias, wi, wf, wo,
                                          h0_hi, h0_lo, h1_hi, h1_lo, ctr);

    // 128 steps (even) => final h lives in the h0 planes
    qt_kernel<<<dim3(8, 16), 256, 0, stream>>>(h0_hi, h0_lo, Mt_hi, Mt_lo, qt);
    dense_out<<<320, 256, 0, stream>>>(qt, h0_hi, h0_lo, W1, b1, W2, b2, out);
}

// Round 7
// 7069.320 us; speedup vs baseline: 1.0715x; 1.0002x over previous
//
#include <hip/hip_runtime.h>

// DualEncoderLSTMDense: dual peephole-LSTM encoders (shared weights) + M-projection + tiny MLP.
// B=256, L=128, E=256, H=512, VOCAB=90000, NUM_NEG=4, forget_bias=2.0.
//
// Round 7: identical to round 6 EXCEPT the barrier poll is an atomic RMW
// (fetch_add of 0) instead of an atomic load. Theory: agent-scope atomicAdd
// bypasses L2 to the coherence point, but atomic LOADs are served from the
// local L2 and return a STALE counter until the line happens to be evicted by
// streamed-W traffic (~one step-time) -> every step stalled ~50us regardless
// of work. An RMW poll is forced to the coherence point and always sees fresh
// values. Numerics identical to rounds 3/5/6.

typedef unsigned short u16;
typedef __attribute__((ext_vector_type(8))) short  s16x8;   // 8 bf16 = one MFMA A/B fragment
typedef __attribute__((ext_vector_type(4))) float  f32x4;

#define MFMA(a, b, c) __builtin_amdgcn_mfma_f32_16x16x32_bf16((a), (b), (c), 0, 0, 0)

__device__ __forceinline__ u16 f2bf(float f) {   // RNE float -> bf16
    union { float f; unsigned u; } v; v.f = f;
    unsigned r = v.u + 0x7FFFu + ((v.u >> 16) & 1u);
    return (u16)(r >> 16);
}
__device__ __forceinline__ float bf2f(u16 h) {
    union { unsigned u; float f; } v; v.u = ((unsigned)h) << 16;
    return v.f;
}
__device__ __forceinline__ float sigm(float x) { return 1.0f / (1.0f + expf(-x)); }

// ---- transpose fp32 [R][C] -> bf16 hi/lo planes [C][R] (R,C multiples of 32) ----
__global__ __launch_bounds__(256) void transpose_split(const float* __restrict__ src,
        u16* __restrict__ dhi, u16* __restrict__ dlo, int R, int C)
{
    __shared__ float tile[32][33];
    const int bx = blockIdx.x * 32;   // src col base
    const int by = blockIdx.y * 32;   // src row base
    for (int i = threadIdx.y; i < 32; i += 8)
        tile[i][threadIdx.x] = src[(size_t)(by + i) * C + bx + threadIdx.x];
    __syncthreads();
    for (int i = threadIdx.y; i < 32; i += 8) {
        float v = tile[threadIdx.x][i];
        u16 hi = f2bf(v);
        size_t o = (size_t)(bx + i) * R + by + threadIdx.x;
        dhi[o] = hi;
        dlo[o] = f2bf(v - bf2f(hi));
    }
}

// ---- zero h0 planes + barrier counters ----
__global__ __launch_bounds__(256) void zero_state(u16* __restrict__ h0_hi,
        u16* __restrict__ h0_lo, unsigned* __restrict__ ctr)
{
    const int i = blockIdx.x * 256 + threadIdx.x;   // grid 1024*256 = 262144
    h0_hi[i] = 0;
    h0_lo[i] = 0;
    if (i < 8) ctr[i * 32] = 0;
}

// ---- persistent LSTM: all 128 steps, both encoders (512 batch rows) ----
// 256 blocks (1/CU): rowTile = bid&7 (64 batch rows), hidTile = bid>>3 (16 hid cols).
__global__ __launch_bounds__(256, 1) void lstm_persist(
        const float* __restrict__ emb, const int* __restrict__ qtok, const int* __restrict__ rtok,
        const int* __restrict__ qlen, const int* __restrict__ rlen,
        const u16* __restrict__ Wt_hi, const u16* __restrict__ Wt_lo,   // [2048][768]
        const float* __restrict__ bias, const float* __restrict__ wi,
        const float* __restrict__ wf, const float* __restrict__ wo,
        u16* __restrict__ h0_hi, u16* __restrict__ h0_lo,
        u16* __restrict__ h1_hi, u16* __restrict__ h1_lo,
        unsigned* __restrict__ ctr)
{
    __shared__ u16 whi_h[32768];   // 64 KiB: W_hi rows [4g*16c] x K 256..767, XOR-swizzled

    const int tid = threadIdx.x, lane = tid & 63, w = tid >> 6;
    const int bid = blockIdx.x;
    const int rowTile = bid & 7, hidTile = bid >> 3;
    const int row0 = rowTile * 64 + w * 16, hid0 = hidTile * 16;
    const int frow = lane & 15, kgrp = lane >> 4;
    const int sw = (frow & 7) << 4;                // LDS XOR swizzle for this lane

    // ---- stage h-part W_hi into LDS (once): 64 rows x 64 chunks of 16B ----
    for (int i = tid; i < 4096; i += 256) {
        const int gc = i >> 6, c16 = i & 63;       // W row, 16B chunk within K-slice
        const int g = gc >> 4, cc = gc & 15;
        const s16x8 v = *(const s16x8*)(Wt_hi + (size_t)(g * 512 + hid0 + cc) * 768 + 256 + c16 * 8);
        *(s16x8*)((char*)whi_h + ((gc * 1024 + c16 * 16) ^ ((gc & 7) << 4))) = v;
    }

    // ---- per-thread constants ----
    const int   ohid = hid0 + frow;
    const float bi  = bias[ohid];
    const float bj  = bias[512 + ohid];
    const float bff = bias[1024 + ohid];
    const float bo  = bias[1536 + ohid];
    const float wiv = wi[ohid], wfv = wf[ohid], wov = wo[ohid];
    const int   arow = row0 + frow;                                 // A-fragment row
    const int*  tokp = (arow < 256) ? (qtok + arow * 128) : (rtok + (arow - 256) * 128);
    const u16*  whi_base[4];
    const u16*  wlo_base[4];
    #pragma unroll
    for (int g = 0; g < 4; ++g) {
        whi_base[g] = Wt_hi + (size_t)(g * 512 + hid0 + frow) * 768;
        wlo_base[g] = Wt_lo + (size_t)(g * 512 + hid0 + frow) * 768;
    }
    int lenv[4];
    #pragma unroll
    for (int r = 0; r < 4; ++r) {
        const int rr = row0 + kgrp * 4 + r;
        lenv[r] = (rr < 256) ? qlen[rr] : rlen[rr - 256];
    }
    float c_reg[4] = {0, 0, 0, 0}, h_reg[4] = {0, 0, 0, 0};

    __syncthreads();

    unsigned* myctr = ctr + rowTile * 32;

    for (int t = 0; t < 128; ++t) {
        const u16* rd_hi = (t & 1) ? h1_hi : h0_hi;
        const u16* rd_lo = (t & 1) ? h1_lo : h0_lo;
        u16*       wr_hi = (t & 1) ? h0_hi : h1_hi;
        u16*       wr_lo = (t & 1) ? h0_lo : h1_lo;

        // ---- x-part FIRST (depends only on tokens; overlaps barrier stragglers) ----
        const int    tok  = tokp[t];
        const float* xrow = emb + (size_t)tok * 256 + kgrp * 8;
        f32x4 fv[16];
        #pragma unroll
        for (int i = 0; i < 16; ++i)
            fv[i] = *(const f32x4*)(xrow + (i >> 1) * 32 + (i & 1) * 4);

        f32x4 acc[4] = {{0,0,0,0},{0,0,0,0},{0,0,0,0},{0,0,0,0}};  // gates i,j,f,o

        // x-part, K 0..255: split fp32 gather into 2 planes; bh/bl streamed; 3 products
        #pragma unroll
        for (int ks = 0; ks < 8; ++ks) {
            const f32x4 v0 = fv[2 * ks], v1 = fv[2 * ks + 1];
            const float vv[8] = {v0[0], v0[1], v0[2], v0[3], v1[0], v1[1], v1[2], v1[3]};
            s16x8 xh, xl;
            #pragma unroll
            for (int e = 0; e < 8; ++e) {
                const u16 hb = f2bf(vv[e]);
                xh[e] = (short)hb;
                xl[e] = (short)f2bf(vv[e] - bf2f(hb));
            }
            const int kk = ks * 32 + kgrp * 8;
            #pragma unroll
            for (int g = 0; g < 4; ++g) {
                const s16x8 bh = *(const s16x8*)(whi_base[g] + kk);
                const s16x8 bl = *(const s16x8*)(wlo_base[g] + kk);
                acc[g] = MFMA(xh, bh, acc[g]);
                acc[g] = MFMA(xl, bh, acc[g]);
                acc[g] = MFMA(xh, bl, acc[g]);
            }
        }

        // ---- barrier wait: all 32 group blocks must have PUBLISHED h(t-1) ----
        // Poll with an atomic RMW (fetch_add 0): forced to the coherence point,
        // always fresh (a plain atomic load can be served stale from local L2).
        if (tid == 0) {
            const unsigned target = 32u * (unsigned)t;
            while (__hip_atomic_fetch_add(myctr, 0u, __ATOMIC_RELAXED, __HIP_MEMORY_SCOPE_AGENT) < target)
                __builtin_amdgcn_s_sleep(1);
        }
        __syncthreads();
        __threadfence();   // acquire: make h(t-1) visible

        const u16* ahp = rd_hi + arow * 512 + kgrp * 8;
        const u16* alp = rd_lo + arow * 512 + kgrp * 8;

        // h-part, K 256..767: bh from LDS, bl streamed; 4 products
        #pragma unroll 2
        for (int ks = 0; ks < 16; ++ks) {
            const int kh = ks * 32;
            const s16x8 ah = *(const s16x8*)(ahp + kh);
            const s16x8 al = *(const s16x8*)(alp + kh);
            #pragma unroll
            for (int g = 0; g < 4; ++g) {
                const int gr = g * 16 + frow;
                const s16x8 bh = *(const s16x8*)((const char*)whi_h + ((gr * 1024 + (kh + kgrp * 8) * 2) ^ sw));
                const s16x8 bl = *(const s16x8*)(wlo_base[g] + 256 + kh + kgrp * 8);
                acc[g] = MFMA(ah, bh, acc[g]);
                acc[g] = MFMA(al, bh, acc[g]);
                acc[g] = MFMA(ah, bl, acc[g]);
                acc[g] = MFMA(al, bl, acc[g]);
            }
        }

        // gates + peepholes + masking (state in registers)
        #pragma unroll
        for (int r = 0; r < 4; ++r) {
            const float cold = c_reg[r];
            const float ig = sigm(acc[0][r] + bi + wiv * cold);
            const float jg = tanhf(acc[1][r] + bj);
            const float fg = sigm(acc[2][r] + bff + wfv * cold + 2.0f);
            const float cn = fg * cold + ig * jg;
            const float og = sigm(acc[3][r] + bo + wov * cn);
            const float hn = og * tanhf(cn);
            const bool upd = (t < lenv[r]);
            c_reg[r] = upd ? cn : c_reg[r];
            h_reg[r] = upd ? hn : h_reg[r];
            const int off = (row0 + kgrp * 4 + r) * 512 + ohid;
            const u16 hb = f2bf(h_reg[r]);
            wr_hi[off] = hb;
            wr_lo[off] = f2bf(h_reg[r] - bf2f(hb));
        }

        // ---- publish: release fence, then one relaxed add per block ----
        __threadfence();   // release: h(t) stores visible before the add
        __syncthreads();
        if (tid == 0)
            __hip_atomic_fetch_add(myctr, 1u, __ATOMIC_RELAXED, __HIP_MEMORY_SCOPE_AGENT);
    }
}

// ---- qt[256][512] = q_h @ M (MFMA, both operands hi+lo, 4 products) ; grid (8,16), 4 waves 2x2 ----
__global__ __launch_bounds__(256) void qt_kernel(
        const u16* __restrict__ h_hi, const u16* __restrict__ h_lo,
        const u16* __restrict__ Mt_hi, const u16* __restrict__ Mt_lo, float* __restrict__ qt)
{
    const int tid = threadIdx.x, lane = tid & 63, w = tid >> 6;
    const int wr = w >> 1, wc = w & 1;
    const int row0 = blockIdx.x * 32 + wr * 16;
    const int col0 = blockIdx.y * 32 + wc * 16;
    const int frow = lane & 15, kgrp = lane >> 4;
    f32x4 acc = {0, 0, 0, 0};
    const u16* aph = h_hi  + (row0 + frow) * 512 + kgrp * 8;
    const u16* apl = h_lo  + (row0 + frow) * 512 + kgrp * 8;
    const u16* bph = Mt_hi + (col0 + frow) * 512 + kgrp * 8;
    const u16* bpl = Mt_lo + (col0 + frow) * 512 + kgrp * 8;
    #pragma unroll 4
    for (int ks = 0; ks < 16; ++ks) {
        s16x8 ah = *(const s16x8*)(aph + ks * 32);
        s16x8 al = *(const s16x8*)(apl + ks * 32);
        s16x8 bh = *(const s16x8*)(bph + ks * 32);
        s16x8 bl = *(const s16x8*)(bpl + ks * 32);
        acc = MFMA(ah, bh, acc);
        acc = MFMA(al, bh, acc);
        acc = MFMA(ah, bl, acc);
        acc = MFMA(al, bl, acc);
    }
    #pragma unroll
    for (int r = 0; r < 4; ++r)
        qt[(row0 + kgrp * 4 + r) * 512 + col0 + frow] = acc[r];
}

// ---- final MLP: 1280 rows, one wave per row ----
__global__ __launch_bounds__(256) void dense_out(const float* __restrict__ qt,
        const u16* __restrict__ h_hi, const u16* __restrict__ h_lo,
        const float* __restrict__ W1, const float* __restrict__ b1,
        const float* __restrict__ W2, const float* __restrict__ b2, float* __restrict__ out)
{
    const int r    = blockIdx.x * 4 + (threadIdx.x >> 6);
    const int lane = threadIdx.x & 63;
    int qi, ri;
    if (r < 256) { qi = r; ri = r; }
    else { const int g = (r - 256) >> 8; const int b = (r - 256) & 255; qi = b; ri = (b + g + 1) & 255; }

    float p[10];
    #pragma unroll
    for (int u = 0; u < 10; ++u) p[u] = 0.0f;
    for (int k = lane; k < 512; k += 64) {
        const float xq = qt[qi * 512 + k];
        #pragma unroll
        for (int u = 0; u < 10; ++u) p[u] += xq * W1[k * 10 + u];
    }
    for (int k = lane; k < 512; k += 64) {
        const int off = (256 + ri) * 512 + k;
        const float xr = bf2f(h_hi[off]) + bf2f(h_lo[off]);
        #pragma unroll
        for (int u = 0; u < 10; ++u) p[u] += xr * W1[(512 + k) * 10 + u];
    }
    #pragma unroll
    for (int off = 32; off; off >>= 1) {
        #pragma unroll
        for (int u = 0; u < 10; ++u) p[u] += __shfl_xor(p[u], off);
    }
    float s = b2[0];
    #pragma unroll
    for (int u = 0; u < 10; ++u) {
        const float h1 = fmaxf(p[u] + b1[u], 0.0f);
        s += h1 * W2[u];
    }
    if (lane == 0) out[r] = fmaxf(s, 0.0f);
}

extern "C" void kernel_launch(void* const* d_in, const int* in_sizes, int n_in,
                              void* d_out, int out_size, void* d_ws, size_t ws_size,
                              hipStream_t stream)
{
    const float* emb  = (const float*)d_in[0];
    const float* Wk   = (const float*)d_in[1];
    const float* bias = (const float*)d_in[2];
    const float* wi   = (const float*)d_in[3];
    const float* wf   = (const float*)d_in[4];
    const float* wo   = (const float*)d_in[5];
    const float* M    = (const float*)d_in[6];
    const float* W1   = (const float*)d_in[7];
    const float* b1   = (const float*)d_in[8];
    const float* W2   = (const float*)d_in[9];
    const float* b2   = (const float*)d_in[10];
    const int*   qtok = (const int*)d_in[11];
    const int*   rtok = (const int*)d_in[12];
    const int*   qlen = (const int*)d_in[13];
    const int*   rlen = (const int*)d_in[14];
    float* out = (float*)d_out;

    // workspace layout (16B-aligned); total ~10 MB
    char* ws = (char*)d_ws;
    u16*      Wt_hi = (u16*)(ws + 0);            // 2048*768*2  = 3,145,728
    u16*      Wt_lo = (u16*)(ws + 3145728);      //               3,145,728
    u16*      Mt_hi = (u16*)(ws + 6291456);      // 512*512*2   =   524,288
    u16*      Mt_lo = (u16*)(ws + 6815744);      //                 524,288
    u16*      h0_hi = (u16*)(ws + 7340032);      //                 524,288
    u16*      h0_lo = (u16*)(ws + 7864320);      //                 524,288
    u16*      h1_hi = (u16*)(ws + 8388608);      //                 524,288
    u16*      h1_lo = (u16*)(ws + 8912896);      //                 524,288
    float*    qt    = (float*)(ws + 9437184);    //                 524,288
    unsigned* ctr   = (unsigned*)(ws + 9961472); // 8 counters @ 128B stride

    transpose_split<<<dim3(64, 24), dim3(32, 8), 0, stream>>>(Wk, Wt_hi, Wt_lo, 768, 2048);
    transpose_split<<<dim3(16, 16), dim3(32, 8), 0, stream>>>(M, Mt_hi, Mt_lo, 512, 512);
    zero_state<<<1024, 256, 0, stream>>>(h0_hi, h0_lo, ctr);

    lstm_persist<<<256, 256, 0, stream>>>(emb, qtok, rtok, qlen, rlen,
                                          Wt_hi, Wt_lo, bias, wi, wf, wo,
                                          h0_hi, h0_lo, h1_hi, h1_lo, ctr);

    // 128 steps (even) => final h lives in the h0 planes
    qt_kernel<<<dim3(8, 16), 256, 0, stream>>>(h0_hi, h0_lo, Mt_hi, Mt_lo, qt);
    dense_out<<<320, 256, 0, stream>>>(qt, h0_hi, h0_lo, W1, b1, W2, b2, out);
}

// Round 8
// 2964.776 us; speedup vs baseline: 2.5550x; 2.3844x over previous
//
#include <hip/hip_runtime.h>

// DualEncoderLSTMDense: dual peephole-LSTM encoders (shared weights) + M-projection + tiny MLP.
// B=256, L=128, E=256, H=512, VOCAB=90000, NUM_NEG=4, forget_bias=2.0.
//
// Round 8: FENCELESS persistent kernel. R5-R7 showed ~57us/step with ~5% busy pipes and
// poll-mechanism changes doing nothing -> suspect the per-step __threadfence() pairs
// (agent fence on multi-XCD = buffer_wbl2 + buffer_inv L2 walks, issued by every wave
// every step, serialized at the TCC). This round removes ALL cache-maintenance ops:
//  - h is exchanged via agent-scope RELAXED atomics (global ops with sc1: L2-bypassing,
//    coherent at MALL, no wbl2/inv). h packed as u32 = (lo16<<16)|hi16, 1 store/element.
//  - release = s_waitcnt vmcnt(0) (+ __syncthreads drain) before a relaxed counter add;
//    acquire = RMW poll (proven fresh in R7) + __syncthreads. No __threadfence anywhere.
// W/emb are read-only (stale L2 harmless). Numerics bit-identical to rounds 3/5/6/7.

typedef unsigned short u16;
typedef unsigned long long u64;
typedef __attribute__((ext_vector_type(8))) short    s16x8;   // 8 bf16 = one MFMA A/B fragment
typedef __attribute__((ext_vector_type(4))) float    f32x4;
typedef __attribute__((ext_vector_type(4))) unsigned u32x4;

#define MFMA(a, b, c) __builtin_amdgcn_mfma_f32_16x16x32_bf16((a), (b), (c), 0, 0, 0)

__device__ __forceinline__ u16 f2bf(float f) {   // RNE float -> bf16
    union { float f; unsigned u; } v; v.f = f;
    unsigned r = v.u + 0x7FFFu + ((v.u >> 16) & 1u);
    return (u16)(r >> 16);
}
__device__ __forceinline__ float bf2f(u16 h) {
    union { unsigned u; float f; } v; v.u = ((unsigned)h) << 16;
    return v.f;
}
__device__ __forceinline__ float sigm(float x) { return 1.0f / (1.0f + expf(-x)); }

// ---- transpose fp32 [R][C] -> bf16 hi/lo planes [C][R] (R,C multiples of 32) ----
__global__ __launch_bounds__(256) void transpose_split(const float* __restrict__ src,
        u16* __restrict__ dhi, u16* __restrict__ dlo, int R, int C)
{
    __shared__ float tile[32][33];
    const int bx = blockIdx.x * 32;   // src col base
    const int by = blockIdx.y * 32;   // src row base
    for (int i = threadIdx.y; i < 32; i += 8)
        tile[i][threadIdx.x] = src[(size_t)(by + i) * C + bx + threadIdx.x];
    __syncthreads();
    for (int i = threadIdx.y; i < 32; i += 8) {
        float v = tile[threadIdx.x][i];
        u16 hi = f2bf(v);
        size_t o = (size_t)(bx + i) * R + by + threadIdx.x;
        dhi[o] = hi;
        dlo[o] = f2bf(v - bf2f(hi));
    }
}

// ---- zero h0 packed plane + barrier counters ----
__global__ __launch_bounds__(256) void zero_state(unsigned* __restrict__ h0p,
        unsigned* __restrict__ ctr)
{
    const int i = blockIdx.x * 256 + threadIdx.x;   // grid 1024*256 = 262144
    h0p[i] = 0;
    if (i < 8) ctr[i * 32] = 0;
}

// ---- persistent LSTM: all 128 steps, both encoders (512 batch rows) ----
// 256 blocks (1/CU): rowTile = bid&7 (64 batch rows), hidTile = bid>>3 (16 hid cols).
__global__ __launch_bounds__(256, 1) void lstm_persist(
        const float* __restrict__ emb, const int* __restrict__ qtok, const int* __restrict__ rtok,
        const int* __restrict__ qlen, const int* __restrict__ rlen,
        const u16* __restrict__ Wt_hi, const u16* __restrict__ Wt_lo,   // [2048][768]
        const float* __restrict__ bias, const float* __restrict__ wi,
        const float* __restrict__ wf, const float* __restrict__ wo,
        unsigned* __restrict__ h0p, unsigned* __restrict__ h1p,         // packed h planes
        unsigned* __restrict__ ctr)
{
    __shared__ u16 whi_h[32768];   // 64 KiB: W_hi rows [4g*16c] x K 256..767, XOR-swizzled

    const int tid = threadIdx.x, lane = tid & 63, w = tid >> 6;
    const int bid = blockIdx.x;
    const int rowTile = bid & 7, hidTile = bid >> 3;
    const int row0 = rowTile * 64 + w * 16, hid0 = hidTile * 16;
    const int frow = lane & 15, kgrp = lane >> 4;
    const int sw = (frow & 7) << 4;                // LDS XOR swizzle for this lane

    // ---- stage h-part W_hi into LDS (once): 64 rows x 64 chunks of 16B ----
    for (int i = tid; i < 4096; i += 256) {
        const int gc = i >> 6, c16 = i & 63;       // W row, 16B chunk within K-slice
        const int g = gc >> 4, cc = gc & 15;
        const s16x8 v = *(const s16x8*)(Wt_hi + (size_t)(g * 512 + hid0 + cc) * 768 + 256 + c16 * 8);
        *(s16x8*)((char*)whi_h + ((gc * 1024 + c16 * 16) ^ ((gc & 7) << 4))) = v;
    }

    // ---- per-thread constants ----
    const int   ohid = hid0 + frow;
    const float bi  = bias[ohid];
    const float bj  = bias[512 + ohid];
    const float bff = bias[1024 + ohid];
    const float bo  = bias[1536 + ohid];
    const float wiv = wi[ohid], wfv = wf[ohid], wov = wo[ohid];
    const int   arow = row0 + frow;                                 // A-fragment row
    const int*  tokp = (arow < 256) ? (qtok + arow * 128) : (rtok + (arow - 256) * 128);
    const u16*  whi_base[4];
    const u16*  wlo_base[4];
    #pragma unroll
    for (int g = 0; g < 4; ++g) {
        whi_base[g] = Wt_hi + (size_t)(g * 512 + hid0 + frow) * 768;
        wlo_base[g] = Wt_lo + (size_t)(g * 512 + hid0 + frow) * 768;
    }
    int lenv[4];
    #pragma unroll
    for (int r = 0; r < 4; ++r) {
        const int rr = row0 + kgrp * 4 + r;
        lenv[r] = (rr < 256) ? qlen[rr] : rlen[rr - 256];
    }
    float c_reg[4] = {0, 0, 0, 0}, h_reg[4] = {0, 0, 0, 0};

    __syncthreads();

    unsigned* myctr = ctr + rowTile * 32;

    for (int t = 0; t < 128; ++t) {
        const unsigned* rd = (t & 1) ? h1p : h0p;
        unsigned*       wr = (t & 1) ? h0p : h1p;

        // ---- x-part FIRST (depends only on tokens; overlaps barrier stragglers) ----
        const int    tok  = tokp[t];
        const float* xrow = emb + (size_t)tok * 256 + kgrp * 8;
        f32x4 fv[16];
        #pragma unroll
        for (int i = 0; i < 16; ++i)
            fv[i] = *(const f32x4*)(xrow + (i >> 1) * 32 + (i & 1) * 4);

        f32x4 acc[4] = {{0,0,0,0},{0,0,0,0},{0,0,0,0},{0,0,0,0}};  // gates i,j,f,o

        // x-part, K 0..255: split fp32 gather into 2 planes; bh/bl streamed; 3 products
        #pragma unroll
        for (int ks = 0; ks < 8; ++ks) {
            const f32x4 v0 = fv[2 * ks], v1 = fv[2 * ks + 1];
            const float vv[8] = {v0[0], v0[1], v0[2], v0[3], v1[0], v1[1], v1[2], v1[3]};
            s16x8 xh, xl;
            #pragma unroll
            for (int e = 0; e < 8; ++e) {
                const u16 hb = f2bf(vv[e]);
                xh[e] = (short)hb;
                xl[e] = (short)f2bf(vv[e] - bf2f(hb));
            }
            const int kk = ks * 32 + kgrp * 8;
            #pragma unroll
            for (int g = 0; g < 4; ++g) {
                const s16x8 bh = *(const s16x8*)(whi_base[g] + kk);
                const s16x8 bl = *(const s16x8*)(wlo_base[g] + kk);
                acc[g] = MFMA(xh, bh, acc[g]);
                acc[g] = MFMA(xl, bh, acc[g]);
                acc[g] = MFMA(xh, bl, acc[g]);
            }
        }

        // ---- wait: all 32 group blocks must have PUBLISHED h(t-1) ----
        // RMW poll at the coherence point (fresh, R7-proven); no fence needed since
        // h itself travels via sc1 atomics below.
        if (tid == 0) {
            const unsigned target = 32u * (unsigned)t;
            while (__hip_atomic_fetch_add(myctr, 0u, __ATOMIC_RELAXED, __HIP_MEMORY_SCOPE_AGENT) < target)
                __builtin_amdgcn_s_sleep(1);
        }
        __syncthreads();

        const unsigned* hrd = rd + arow * 512 + kgrp * 8;

        // h-part, K 256..767: A from packed-h agent atomics (fresh at MALL); bh LDS, bl streamed
        #pragma unroll 2
        for (int ks = 0; ks < 16; ++ks) {
            const int kh = ks * 32;
            s16x8 ah, al;
            #pragma unroll
            for (int i = 0; i < 4; ++i) {
                const u64 v = __hip_atomic_load((const u64*)(hrd + kh + 2 * i),
                                                __ATOMIC_RELAXED, __HIP_MEMORY_SCOPE_AGENT);
                const unsigned w0 = (unsigned)v, w1 = (unsigned)(v >> 32);
                ah[2 * i]     = (short)(u16)w0;
                al[2 * i]     = (short)(u16)(w0 >> 16);
                ah[2 * i + 1] = (short)(u16)w1;
                al[2 * i + 1] = (short)(u16)(w1 >> 16);
            }
            #pragma unroll
            for (int g = 0; g < 4; ++g) {
                const int gr = g * 16 + frow;
                const s16x8 bh = *(const s16x8*)((const char*)whi_h + ((gr * 1024 + (kh + kgrp * 8) * 2) ^ sw));
                const s16x8 bl = *(const s16x8*)(wlo_base[g] + 256 + kh + kgrp * 8);
                acc[g] = MFMA(ah, bh, acc[g]);
                acc[g] = MFMA(al, bh, acc[g]);
                acc[g] = MFMA(ah, bl, acc[g]);
                acc[g] = MFMA(al, bl, acc[g]);
            }
        }

        // gates + peepholes + masking (state in registers); publish h packed via sc1 store
        #pragma unroll
        for (int r = 0; r < 4; ++r) {
            const float cold = c_reg[r];
            const float ig = sigm(acc[0][r] + bi + wiv * cold);
            const float jg = tanhf(acc[1][r] + bj);
            const float fg = sigm(acc[2][r] + bff + wfv * cold + 2.0f);
            const float cn = fg * cold + ig * jg;
            const float og = sigm(acc[3][r] + bo + wov * cn);
            const float hn = og * tanhf(cn);
            const bool upd = (t < lenv[r]);
            c_reg[r] = upd ? cn : c_reg[r];
            h_reg[r] = upd ? hn : h_reg[r];
            const int off = (row0 + kgrp * 4 + r) * 512 + ohid;
            const u16 hb = f2bf(h_reg[r]);
            const u16 lb = f2bf(h_reg[r] - bf2f(hb));
            __hip_atomic_store(wr + off, ((unsigned)lb << 16) | (unsigned)hb,
                               __ATOMIC_RELAXED, __HIP_MEMORY_SCOPE_AGENT);
        }

        // ---- publish: drain this wave's stores (vmcnt), block-converge, one relaxed add ----
        asm volatile("s_waitcnt vmcnt(0)" ::: "memory");
        __syncthreads();
        if (tid == 0)
            __hip_atomic_fetch_add(myctr, 1u, __ATOMIC_RELAXED, __HIP_MEMORY_SCOPE_AGENT);
    }
}

// ---- qt[256][512] = q_h @ M (MFMA, h from packed plane, M hi+lo, 4 products) ----
// grid (8,16), 4 waves 2x2
__global__ __launch_bounds__(256) void qt_kernel(
        const unsigned* __restrict__ hpk,
        const u16* __restrict__ Mt_hi, const u16* __restrict__ Mt_lo, float* __restrict__ qt)
{
    const int tid = threadIdx.x, lane = tid & 63, w = tid >> 6;
    const int wr = w >> 1, wc = w & 1;
    const int row0 = blockIdx.x * 32 + wr * 16;
    const int col0 = blockIdx.y * 32 + wc * 16;
    const int frow = lane & 15, kgrp = lane >> 4;
    f32x4 acc = {0, 0, 0, 0};
    const unsigned* ap = hpk + (row0 + frow) * 512 + kgrp * 8;
    const u16* bph = Mt_hi + (col0 + frow) * 512 + kgrp * 8;
    const u16* bpl = Mt_lo + (col0 + frow) * 512 + kgrp * 8;
    #pragma unroll 4
    for (int ks = 0; ks < 16; ++ks) {
        const u32x4 a0 = *(const u32x4*)(ap + ks * 32);
        const u32x4 a1 = *(const u32x4*)(ap + ks * 32 + 4);
        s16x8 ah, al;
        #pragma unroll
        for (int i = 0; i < 4; ++i) {
            ah[i]     = (short)(u16)a0[i];
            al[i]     = (short)(u16)(a0[i] >> 16);
            ah[4 + i] = (short)(u16)a1[i];
            al[4 + i] = (short)(u16)(a1[i] >> 16);
        }
        const s16x8 bh = *(const s16x8*)(bph + ks * 32);
        const s16x8 bl = *(const s16x8*)(bpl + ks * 32);
        acc = MFMA(ah, bh, acc);
        acc = MFMA(al, bh, acc);
        acc = MFMA(ah, bl, acc);
        acc = MFMA(al, bl, acc);
    }
    #pragma unroll
    for (int r = 0; r < 4; ++r)
        qt[(row0 + kgrp * 4 + r) * 512 + col0 + frow] = acc[r];
}

// ---- final MLP: 1280 rows, one wave per row ----
__global__ __launch_bounds__(256) void dense_out(const float* __restrict__ qt,
        const unsigned* __restrict__ hpk,
        const float* __restrict__ W1, const float* __restrict__ b1,
        const float* __restrict__ W2, const float* __restrict__ b2, float* __restrict__ out)
{
    const int r    = blockIdx.x * 4 + (threadIdx.x >> 6);
    const int lane = threadIdx.x & 63;
    int qi, ri;
    if (r < 256) { qi = r; ri = r; }
    else { const int g = (r - 256) >> 8; const int b = (r - 256) & 255; qi = b; ri = (b + g + 1) & 255; }

    float p[10];
    #pragma unroll
    for (int u = 0; u < 10; ++u) p[u] = 0.0f;
    for (int k = lane; k < 512; k += 64) {
        const float xq = qt[qi * 512 + k];
        #pragma unroll
        for (int u = 0; u < 10; ++u) p[u] += xq * W1[k * 10 + u];
    }
    for (int k = lane; k < 512; k += 64) {
        const unsigned v = hpk[(256 + ri) * 512 + k];
        const float xr = bf2f((u16)v) + bf2f((u16)(v >> 16));
        #pragma unroll
        for (int u = 0; u < 10; ++u) p[u] += xr * W1[(512 + k) * 10 + u];
    }
    #pragma unroll
    for (int off = 32; off; off >>= 1) {
        #pragma unroll
        for (int u = 0; u < 10; ++u) p[u] += __shfl_xor(p[u], off);
    }
    float s = b2[0];
    #pragma unroll
    for (int u = 0; u < 10; ++u) {
        const float h1 = fmaxf(p[u] + b1[u], 0.0f);
        s += h1 * W2[u];
    }
    if (lane == 0) out[r] = fmaxf(s, 0.0f);
}

extern "C" void kernel_launch(void* const* d_in, const int* in_sizes, int n_in,
                              void* d_out, int out_size, void* d_ws, size_t ws_size,
                              hipStream_t stream)
{
    const float* emb  = (const float*)d_in[0];
    const float* Wk   = (const float*)d_in[1];
    const float* bias = (const float*)d_in[2];
    const float* wi   = (const float*)d_in[3];
    const float* wf   = (const float*)d_in[4];
    const float* wo   = (const float*)d_in[5];
    const float* M    = (const float*)d_in[6];
    const float* W1   = (const float*)d_in[7];
    const float* b1   = (const float*)d_in[8];
    const float* W2   = (const float*)d_in[9];
    const float* b2   = (const float*)d_in[10];
    const int*   qtok = (const int*)d_in[11];
    const int*   rtok = (const int*)d_in[12];
    const int*   qlen = (const int*)d_in[13];
    const int*   rlen = (const int*)d_in[14];
    float* out = (float*)d_out;

    // workspace layout (16B-aligned); total ~10.5 MB
    char* ws = (char*)d_ws;
    u16*      Wt_hi = (u16*)(ws + 0);            // 2048*768*2  = 3,145,728
    u16*      Wt_lo = (u16*)(ws + 3145728);      //               3,145,728
    u16*      Mt_hi = (u16*)(ws + 6291456);      // 512*512*2   =   524,288
    u16*      Mt_lo = (u16*)(ws + 6815744);      //                 524,288
    unsigned* h0p   = (unsigned*)(ws + 7340032); // 512*512*4   = 1,048,576 (packed lo|hi)
    unsigned* h1p   = (unsigned*)(ws + 8388608); //               1,048,576
    float*    qt    = (float*)(ws + 9437184);    //                 524,288
    unsigned* ctr   = (unsigned*)(ws + 9961472); // 8 counters @ 128B stride

    transpose_split<<<dim3(64, 24), dim3(32, 8), 0, stream>>>(Wk, Wt_hi, Wt_lo, 768, 2048);
    transpose_split<<<dim3(16, 16), dim3(32, 8), 0, stream>>>(M, Mt_hi, Mt_lo, 512, 512);
    zero_state<<<1024, 256, 0, stream>>>(h0p, ctr);

    lstm_persist<<<256, 256, 0, stream>>>(emb, qtok, rtok, qlen, rlen,
                                          Wt_hi, Wt_lo, bias, wi, wf, wo,
                                          h0p, h1p, ctr);

    // 128 steps (even) => final h lives in h0p
    qt_kernel<<<dim3(8, 16), 256, 0, stream>>>(h0p, Mt_hi, Mt_lo, qt);
    dense_out<<<320, 256, 0, stream>>>(qt, h0p, W1, b1, W2, b2, out);
}

// Round 9
// 2942.172 us; speedup vs baseline: 2.5746x; 1.0077x over previous
//
#include <hip/hip_runtime.h>

// DualEncoderLSTMDense: dual peephole-LSTM encoders (shared weights) + M-projection + tiny MLP.
// B=256, L=128, E=256, H=512, VOCAB=90000, NUM_NEG=4, forget_bias=2.0.
//
// Round 9: hoist the non-recurrent x-part (z_x = x @ W[:256]) out of the persistent loop
// into a bulk GEMM (zx[128][512][2048] fp32, 512MB ws, runtime-gated on ws_size with exact
// R8 fallback). The recurrent loop starts acc from zx (loads issued pre-barrier -> HBM
// latency hidden under the poll wait) and per step does only: poll -> h-load (sc1/MALL)
// -> 256 MFMA -> gates -> publish. zx GEMM uses the bit-identical MFMA chain (same order,
// acc from 0) so output is bit-for-bit identical to R8. Poll = relaxed loads + RMW every
// 8th iter (kills 32-way RMW serialization at the coherence point, bounds staleness).

typedef unsigned short u16;
typedef unsigned long long u64;
typedef __attribute__((ext_vector_type(8))) short    s16x8;   // 8 bf16 = one MFMA A/B fragment
typedef __attribute__((ext_vector_type(4))) float    f32x4;
typedef __attribute__((ext_vector_type(4))) unsigned u32x4;

#define MFMA(a, b, c) __builtin_amdgcn_mfma_f32_16x16x32_bf16((a), (b), (c), 0, 0, 0)

__device__ __forceinline__ u16 f2bf(float f) {   // RNE float -> bf16
    union { float f; unsigned u; } v; v.f = f;
    unsigned r = v.u + 0x7FFFu + ((v.u >> 16) & 1u);
    return (u16)(r >> 16);
}
__device__ __forceinline__ float bf2f(u16 h) {
    union { unsigned u; float f; } v; v.u = ((unsigned)h) << 16;
    return v.f;
}
__device__ __forceinline__ float sigm(float x) { return 1.0f / (1.0f + expf(-x)); }

// ---- transpose fp32 [R][C] -> bf16 hi/lo planes [C][R] (R,C multiples of 32) ----
__global__ __launch_bounds__(256) void transpose_split(const float* __restrict__ src,
        u16* __restrict__ dhi, u16* __restrict__ dlo, int R, int C)
{
    __shared__ float tile[32][33];
    const int bx = blockIdx.x * 32;   // src col base
    const int by = blockIdx.y * 32;   // src row base
    for (int i = threadIdx.y; i < 32; i += 8)
        tile[i][threadIdx.x] = src[(size_t)(by + i) * C + bx + threadIdx.x];
    __syncthreads();
    for (int i = threadIdx.y; i < 32; i += 8) {
        float v = tile[threadIdx.x][i];
        u16 hi = f2bf(v);
        size_t o = (size_t)(bx + i) * R + by + threadIdx.x;
        dhi[o] = hi;
        dlo[o] = f2bf(v - bf2f(hi));
    }
}

// ---- zero h0 packed plane + barrier counters ----
__global__ __launch_bounds__(256) void zero_state(unsigned* __restrict__ h0p,
        unsigned* __restrict__ ctr)
{
    const int i = blockIdx.x * 256 + threadIdx.x;   // grid 1024*256 = 262144
    h0p[i] = 0;
    if (i < 8) ctr[i * 32] = 0;
}

// ---- bulk x-part GEMM: zx[t][row][gatecol] = x(t,row) @ W[:256] (hi/lo, 3 products) ----
// grid (32 hidTile, 8 rowTile, 128 t), block 256 = 4 waves x 16 rows. Bit-identical
// MFMA chain to the R8 in-loop x-part (acc from 0, same ks/g/product order).
__global__ __launch_bounds__(256) void zx_kernel(
        const float* __restrict__ emb, const int* __restrict__ qtok, const int* __restrict__ rtok,
        const u16* __restrict__ Wt_hi, const u16* __restrict__ Wt_lo, float* __restrict__ zx)
{
    const int tid = threadIdx.x, lane = tid & 63, w = tid >> 6;
    const int hidTile = blockIdx.x, rowTile = blockIdx.y, t = blockIdx.z;
    const int row0 = rowTile * 64 + w * 16, hid0 = hidTile * 16;
    const int frow = lane & 15, kgrp = lane >> 4;
    const int ohid = hid0 + frow;
    const int arow = row0 + frow;
    const int tok  = (arow < 256) ? qtok[arow * 128 + t] : rtok[(arow - 256) * 128 + t];
    const float* xrow = emb + (size_t)tok * 256 + kgrp * 8;

    const u16* whi_base[4];
    const u16* wlo_base[4];
    #pragma unroll
    for (int g = 0; g < 4; ++g) {
        whi_base[g] = Wt_hi + (size_t)(g * 512 + hid0 + frow) * 768;
        wlo_base[g] = Wt_lo + (size_t)(g * 512 + hid0 + frow) * 768;
    }

    f32x4 fv[16];
    #pragma unroll
    for (int i = 0; i < 16; ++i)
        fv[i] = *(const f32x4*)(xrow + (i >> 1) * 32 + (i & 1) * 4);

    f32x4 acc[4] = {{0,0,0,0},{0,0,0,0},{0,0,0,0},{0,0,0,0}};
    #pragma unroll
    for (int ks = 0; ks < 8; ++ks) {
        const f32x4 v0 = fv[2 * ks], v1 = fv[2 * ks + 1];
        const float vv[8] = {v0[0], v0[1], v0[2], v0[3], v1[0], v1[1], v1[2], v1[3]};
        s16x8 xh, xl;
        #pragma unroll
        for (int e = 0; e < 8; ++e) {
            const u16 hb = f2bf(vv[e]);
            xh[e] = (short)hb;
            xl[e] = (short)f2bf(vv[e] - bf2f(hb));
        }
        const int kk = ks * 32 + kgrp * 8;
        #pragma unroll
        for (int g = 0; g < 4; ++g) {
            const s16x8 bh = *(const s16x8*)(whi_base[g] + kk);
            const s16x8 bl = *(const s16x8*)(wlo_base[g] + kk);
            acc[g] = MFMA(xh, bh, acc[g]);
            acc[g] = MFMA(xl, bh, acc[g]);
            acc[g] = MFMA(xh, bl, acc[g]);
        }
    }

    float* zp = zx + ((size_t)t * 512 + row0 + kgrp * 4) * 2048;
    #pragma unroll
    for (int g = 0; g < 4; ++g) {
        #pragma unroll
        for (int r = 0; r < 4; ++r)
            zp[r * 2048 + g * 512 + ohid] = acc[g][r];
    }
}

// ---- persistent LSTM: all 128 steps, both encoders (512 batch rows) ----
// 256 blocks (1/CU): rowTile = bid&7 (64 batch rows), hidTile = bid>>3 (16 hid cols).
// USE_ZX=1: acc starts from precomputed zx (loads issued before the barrier).
template<int USE_ZX>
__global__ __launch_bounds__(256, 1) void lstm_persist(
        const float* __restrict__ emb, const int* __restrict__ qtok, const int* __restrict__ rtok,
        const int* __restrict__ qlen, const int* __restrict__ rlen,
        const u16* __restrict__ Wt_hi, const u16* __restrict__ Wt_lo,   // [2048][768]
        const float* __restrict__ bias, const float* __restrict__ wi,
        const float* __restrict__ wf, const float* __restrict__ wo,
        unsigned* __restrict__ h0p, unsigned* __restrict__ h1p,         // packed h planes
        unsigned* __restrict__ ctr, const float* __restrict__ zx)
{
    __shared__ u16 whi_h[32768];   // 64 KiB: W_hi rows [4g*16c] x K 256..767, XOR-swizzled

    const int tid = threadIdx.x, lane = tid & 63, w = tid >> 6;
    const int bid = blockIdx.x;
    const int rowTile = bid & 7, hidTile = bid >> 3;
    const int row0 = rowTile * 64 + w * 16, hid0 = hidTile * 16;
    const int frow = lane & 15, kgrp = lane >> 4;
    const int sw = (frow & 7) << 4;                // LDS XOR swizzle for this lane

    // ---- stage h-part W_hi into LDS (once): 64 rows x 64 chunks of 16B ----
    for (int i = tid; i < 4096; i += 256) {
        const int gc = i >> 6, c16 = i & 63;       // W row, 16B chunk within K-slice
        const int g = gc >> 4, cc = gc & 15;
        const s16x8 v = *(const s16x8*)(Wt_hi + (size_t)(g * 512 + hid0 + cc) * 768 + 256 + c16 * 8);
        *(s16x8*)((char*)whi_h + ((gc * 1024 + c16 * 16) ^ ((gc & 7) << 4))) = v;
    }

    // ---- per-thread constants ----
    const int   ohid = hid0 + frow;
    const float bi  = bias[ohid];
    const float bj  = bias[512 + ohid];
    const float bff = bias[1024 + ohid];
    const float bo  = bias[1536 + ohid];
    const float wiv = wi[ohid], wfv = wf[ohid], wov = wo[ohid];
    const int   arow = row0 + frow;                                 // A-fragment row
    const int*  tokp = (arow < 256) ? (qtok + arow * 128) : (rtok + (arow - 256) * 128);
    const u16*  whi_base[4];
    const u16*  wlo_base[4];
    #pragma unroll
    for (int g = 0; g < 4; ++g) {
        whi_base[g] = Wt_hi + (size_t)(g * 512 + hid0 + frow) * 768;
        wlo_base[g] = Wt_lo + (size_t)(g * 512 + hid0 + frow) * 768;
    }
    int lenv[4];
    #pragma unroll
    for (int r = 0; r < 4; ++r) {
        const int rr = row0 + kgrp * 4 + r;
        lenv[r] = (rr < 256) ? qlen[rr] : rlen[rr - 256];
    }
    float c_reg[4] = {0, 0, 0, 0}, h_reg[4] = {0, 0, 0, 0};

    __syncthreads();

    unsigned* myctr = ctr + rowTile * 32;

    for (int t = 0; t < 128; ++t) {
        const unsigned* rd = (t & 1) ? h1p : h0p;
        unsigned*       wr = (t & 1) ? h0p : h1p;

        f32x4 acc[4];

        if constexpr (USE_ZX) {
            // acc init from precomputed zx; loads issued BEFORE the barrier so the
            // HBM latency hides under the poll wait.
            const float* zp = zx + ((size_t)t * 512 + row0 + kgrp * 4) * 2048;
            #pragma unroll
            for (int g = 0; g < 4; ++g) {
                const int gc = g * 512 + ohid;
                acc[g][0] = zp[gc];
                acc[g][1] = zp[2048 + gc];
                acc[g][2] = zp[2 * 2048 + gc];
                acc[g][3] = zp[3 * 2048 + gc];
            }
        } else {
            // ---- x-part inline (R8 path) ----
            const int    tok  = tokp[t];
            const float* xrow = emb + (size_t)tok * 256 + kgrp * 8;
            f32x4 fv[16];
            #pragma unroll
            for (int i = 0; i < 16; ++i)
                fv[i] = *(const f32x4*)(xrow + (i >> 1) * 32 + (i & 1) * 4);

            #pragma unroll
            for (int g = 0; g < 4; ++g) acc[g] = f32x4{0, 0, 0, 0};

            #pragma unroll
            for (int ks = 0; ks < 8; ++ks) {
                const f32x4 v0 = fv[2 * ks], v1 = fv[2 * ks + 1];
                const float vv[8] = {v0[0], v0[1], v0[2], v0[3], v1[0], v1[1], v1[2], v1[3]};
                s16x8 xh, xl;
                #pragma unroll
                for (int e = 0; e < 8; ++e) {
                    const u16 hb = f2bf(vv[e]);
                    xh[e] = (short)hb;
                    xl[e] = (short)f2bf(vv[e] - bf2f(hb));
                }
                const int kk = ks * 32 + kgrp * 8;
                #pragma unroll
                for (int g = 0; g < 4; ++g) {
                    const s16x8 bh = *(const s16x8*)(whi_base[g] + kk);
                    const s16x8 bl = *(const s16x8*)(wlo_base[g] + kk);
                    acc[g] = MFMA(xh, bh, acc[g]);
                    acc[g] = MFMA(xl, bh, acc[g]);
                    acc[g] = MFMA(xh, bl, acc[g]);
                }
            }
        }

        // ---- wait: all 32 group blocks must have PUBLISHED h(t-1) ----
        // Relaxed-load poll (no RMW serialization); forced RMW every 8th iter
        // bounds any staleness. h itself travels via sc1 atomics (always fresh).
        if (tid == 0) {
            const unsigned target = 32u * (unsigned)t;
            int it = 0;
            for (;;) {
                const unsigned v = ((it & 7) == 7)
                    ? __hip_atomic_fetch_add(myctr, 0u, __ATOMIC_RELAXED, __HIP_MEMORY_SCOPE_AGENT)
                    : __hip_atomic_load(myctr, __ATOMIC_RELAXED, __HIP_MEMORY_SCOPE_AGENT);
                if (v >= target) break;
                ++it;
                __builtin_amdgcn_s_sleep(1);
            }
        }
        __syncthreads();

        const unsigned* hrd = rd + arow * 512 + kgrp * 8;

        // h-part, K 256..767: A from packed-h agent atomics (fresh at MALL); bh LDS, bl streamed
        #pragma unroll 2
        for (int ks = 0; ks < 16; ++ks) {
            const int kh = ks * 32;
            s16x8 ah, al;
            #pragma unroll
            for (int i = 0; i < 4; ++i) {
                const u64 v = __hip_atomic_load((const u64*)(hrd + kh + 2 * i),
                                                __ATOMIC_RELAXED, __HIP_MEMORY_SCOPE_AGENT);
                const unsigned w0 = (unsigned)v, w1 = (unsigned)(v >> 32);
                ah[2 * i]     = (short)(u16)w0;
                al[2 * i]     = (short)(u16)(w0 >> 16);
                ah[2 * i + 1] = (short)(u16)w1;
                al[2 * i + 1] = (short)(u16)(w1 >> 16);
            }
            #pragma unroll
            for (int g = 0; g < 4; ++g) {
                const int gr = g * 16 + frow;
                const s16x8 bh = *(const s16x8*)((const char*)whi_h + ((gr * 1024 + (kh + kgrp * 8) * 2) ^ sw));
                const s16x8 bl = *(const s16x8*)(wlo_base[g] + 256 + kh + kgrp * 8);
                acc[g] = MFMA(ah, bh, acc[g]);
                acc[g] = MFMA(al, bh, acc[g]);
                acc[g] = MFMA(ah, bl, acc[g]);
                acc[g] = MFMA(al, bl, acc[g]);
            }
        }

        // gates + peepholes + masking (state in registers); publish h packed via sc1 store
        #pragma unroll
        for (int r = 0; r < 4; ++r) {
            const float cold = c_reg[r];
            const float ig = sigm(acc[0][r] + bi + wiv * cold);
            const float jg = tanhf(acc[1][r] + bj);
            const float fg = sigm(acc[2][r] + bff + wfv * cold + 2.0f);
            const float cn = fg * cold + ig * jg;
            const float og = sigm(acc[3][r] + bo + wov * cn);
            const float hn = og * tanhf(cn);
            const bool upd = (t < lenv[r]);
            c_reg[r] = upd ? cn : c_reg[r];
            h_reg[r] = upd ? hn : h_reg[r];
            const int off = (row0 + kgrp * 4 + r) * 512 + ohid;
            const u16 hb = f2bf(h_reg[r]);
            const u16 lb = f2bf(h_reg[r] - bf2f(hb));
            __hip_atomic_store(wr + off, ((unsigned)lb << 16) | (unsigned)hb,
                               __ATOMIC_RELAXED, __HIP_MEMORY_SCOPE_AGENT);
        }

        // ---- publish: drain this wave's stores (vmcnt), block-converge, one relaxed add ----
        asm volatile("s_waitcnt vmcnt(0)" ::: "memory");
        __syncthreads();
        if (tid == 0)
            __hip_atomic_fetch_add(myctr, 1u, __ATOMIC_RELAXED, __HIP_MEMORY_SCOPE_AGENT);
    }
}

// ---- qt[256][512] = q_h @ M (MFMA, h from packed plane, M hi+lo, 4 products) ----
// grid (8,16), 4 waves 2x2
__global__ __launch_bounds__(256) void qt_kernel(
        const unsigned* __restrict__ hpk,
        const u16* __restrict__ Mt_hi, const u16* __restrict__ Mt_lo, float* __restrict__ qt)
{
    const int tid = threadIdx.x, lane = tid & 63, w = tid >> 6;
    const int wr = w >> 1, wc = w & 1;
    const int row0 = blockIdx.x * 32 + wr * 16;
    const int col0 = blockIdx.y * 32 + wc * 16;
    const int frow = lane & 15, kgrp = lane >> 4;
    f32x4 acc = {0, 0, 0, 0};
    const unsigned* ap = hpk + (row0 + frow) * 512 + kgrp * 8;
    const u16* bph = Mt_hi + (col0 + frow) * 512 + kgrp * 8;
    const u16* bpl = Mt_lo + (col0 + frow) * 512 + kgrp * 8;
    #pragma unroll 4
    for (int ks = 0; ks < 16; ++ks) {
        const u32x4 a0 = *(const u32x4*)(ap + ks * 32);
        const u32x4 a1 = *(const u32x4*)(ap + ks * 32 + 4);
        s16x8 ah, al;
        #pragma unroll
        for (int i = 0; i < 4; ++i) {
            ah[i]     = (short)(u16)a0[i];
            al[i]     = (short)(u16)(a0[i] >> 16);
            ah[4 + i] = (short)(u16)a1[i];
            al[4 + i] = (short)(u16)(a1[i] >> 16);
        }
        const s16x8 bh = *(const s16x8*)(bph + ks * 32);
        const s16x8 bl = *(const s16x8*)(bpl + ks * 32);
        acc = MFMA(ah, bh, acc);
        acc = MFMA(al, bh, acc);
        acc = MFMA(ah, bl, acc);
        acc = MFMA(al, bl, acc);
    }
    #pragma unroll
    for (int r = 0; r < 4; ++r)
        qt[(row0 + kgrp * 4 + r) * 512 + col0 + frow] = acc[r];
}

// ---- final MLP: 1280 rows, one wave per row ----
__global__ __launch_bounds__(256) void dense_out(const float* __restrict__ qt,
        const unsigned* __restrict__ hpk,
        const float* __restrict__ W1, const float* __restrict__ b1,
        const float* __restrict__ W2, const float* __restrict__ b2, float* __restrict__ out)
{
    const int r    = blockIdx.x * 4 + (threadIdx.x >> 6);
    const int lane = threadIdx.x & 63;
    int qi, ri;
    if (r < 256) { qi = r; ri = r; }
    else { const int g = (r - 256) >> 8; const int b = (r - 256) & 255; qi = b; ri = (b + g + 1) & 255; }

    float p[10];
    #pragma unroll
    for (int u = 0; u < 10; ++u) p[u] = 0.0f;
    for (int k = lane; k < 512; k += 64) {
        const float xq = qt[qi * 512 + k];
        #pragma unroll
        for (int u = 0; u < 10; ++u) p[u] += xq * W1[k * 10 + u];
    }
    for (int k = lane; k < 512; k += 64) {
        const unsigned v = hpk[(256 + ri) * 512 + k];
        const float xr = bf2f((u16)v) + bf2f((u16)(v >> 16));
        #pragma unroll
        for (int u = 0; u < 10; ++u) p[u] += xr * W1[(512 + k) * 10 + u];
    }
    #pragma unroll
    for (int off = 32; off; off >>= 1) {
        #pragma unroll
        for (int u = 0; u < 10; ++u) p[u] += __shfl_xor(p[u], off);
    }
    float s = b2[0];
    #pragma unroll
    for (int u = 0; u < 10; ++u) {
        const float h1 = fmaxf(p[u] + b1[u], 0.0f);
        s += h1 * W2[u];
    }
    if (lane == 0) out[r] = fmaxf(s, 0.0f);
}

extern "C" void kernel_launch(void* const* d_in, const int* in_sizes, int n_in,
                              void* d_out, int out_size, void* d_ws, size_t ws_size,
                              hipStream_t stream)
{
    const float* emb  = (const float*)d_in[0];
    const float* Wk   = (const float*)d_in[1];
    const float* bias = (const float*)d_in[2];
    const float* wi   = (const float*)d_in[3];
    const float* wf   = (const float*)d_in[4];
    const float* wo   = (const float*)d_in[5];
    const float* M    = (const float*)d_in[6];
    const float* W1   = (const float*)d_in[7];
    const float* b1   = (const float*)d_in[8];
    const float* W2   = (const float*)d_in[9];
    const float* b2   = (const float*)d_in[10];
    const int*   qtok = (const int*)d_in[11];
    const int*   rtok = (const int*)d_in[12];
    const int*   qlen = (const int*)d_in[13];
    const int*   rlen = (const int*)d_in[14];
    float* out = (float*)d_out;

    // workspace layout (16B-aligned); base ~10 MB, zx (optional) 512 MB
    char* ws = (char*)d_ws;
    u16*      Wt_hi = (u16*)(ws + 0);            // 2048*768*2  = 3,145,728
    u16*      Wt_lo = (u16*)(ws + 3145728);      //               3,145,728
    u16*      Mt_hi = (u16*)(ws + 6291456);      // 512*512*2   =   524,288
    u16*      Mt_lo = (u16*)(ws + 6815744);      //                 524,288
    unsigned* h0p   = (unsigned*)(ws + 7340032); // 512*512*4   = 1,048,576 (packed lo|hi)
    unsigned* h1p   = (unsigned*)(ws + 8388608); //               1,048,576
    float*    qt    = (float*)(ws + 9437184);    //                 524,288
    unsigned* ctr   = (unsigned*)(ws + 9961472); // 8 counters @ 128B stride
    float*    zx    = (float*)(ws + 10485760);   // 128*512*2048*4 = 536,870,912 (optional)
    const size_t NEED_ZX = 10485760ull + 536870912ull;

    transpose_split<<<dim3(64, 24), dim3(32, 8), 0, stream>>>(Wk, Wt_hi, Wt_lo, 768, 2048);
    transpose_split<<<dim3(16, 16), dim3(32, 8), 0, stream>>>(M, Mt_hi, Mt_lo, 512, 512);
    zero_state<<<1024, 256, 0, stream>>>(h0p, ctr);

    if (ws_size >= NEED_ZX) {
        zx_kernel<<<dim3(32, 8, 128), 256, 0, stream>>>(emb, qtok, rtok, Wt_hi, Wt_lo, zx);
        lstm_persist<1><<<256, 256, 0, stream>>>(emb, qtok, rtok, qlen, rlen,
                                                 Wt_hi, Wt_lo, bias, wi, wf, wo,
                                                 h0p, h1p, ctr, zx);
    } else {
        lstm_persist<0><<<256, 256, 0, stream>>>(emb, qtok, rtok, qlen, rlen,
                                                 Wt_hi, Wt_lo, bias, wi, wf, wo,
                                                 h0p, h1p, ctr, zx);
    }

    // 128 steps (even) => final h lives in h0p
    qt_kernel<<<dim3(8, 16), 256, 0, stream>>>(h0p, Mt_hi, Mt_lo, qt);
    dense_out<<<320, 256, 0, stream>>>(qt, h0p, W1, b1, W2, b2, out);
}